// Round 16
// baseline (49.465 us; speedup 1.0000x reference)
//
#include <hip/hip_runtime.h>

// NormalizingFlow: 4 layers of monotonic linear-rational splines (pyro-style),
// B=262144 rows, D=64 dims, K=8 bins.
//
// Composed 4-layer chain per dim = piecewise-Mobius: 61 interior pieces +
// identity pieces (x<-3 row 0, x>=3 rows 62/63), det-normalized (det=1)
// ABSOLUTE fp32 coeffs, 64-row table. Main kernel (lane = dim, natural
// columns, conflict-free): linear counts on RAW x —
//   row = (x>=-3) + sum(x>=B[8m], m=1..7) + sum(x>=B[8c+1..8c+7])
// + one b128 coeff gather + Mobius; lad = -2 ln|den|; DPP reduce.
// R16: unit widened 2->4 rows (12 LDS reads in flight/STEP, per-unit
// overhead halved, float4 log-det store); same 2-slot fenced pipeline.

#define BATCH 262144
#define DIM   64
#define NLAY  4
#define NK    8

// float offsets in d_ws (units: floats from base)
#define OFF_KN0 0       // [8][64][4] boundary slots B[8c+0..3]
#define OFF_KN1 2048    // [8][64][4] boundary slots B[8c+4..7]
#define OFF_CRS 4096    // [7][64] coarse knots B[8],B[16],...,B[56]
#define OFF_CF0 4544    // [64][64][4] piece coeffs (A,B,C,D); rows 0,62,63 id

// Fused precompute: one block per dim d (64 blocks x 64 threads).
// Phase 1 parallelized over 32 threads: t = l*8 + k (layer l, bin k).
__global__ void nf_pre(const float* __restrict__ uw, const float* __restrict__ uh,
                       const float* __restrict__ ud, const float* __restrict__ ul,
                       float* __restrict__ F) {
  __shared__ double Lb[NLAY][17], Ly[NLAY][17], LM[NLAY][16][4], Ld[NLAY][16];
  __shared__ double sx[64], Fb[65];
  int d = blockIdx.x;
  int t = threadIdx.x;

  if (t < 32) {
    int l = t >> 3, k = t & 7;
    const float* pw  = uw + (l*DIM + d)*NK;
    const float* ph  = uh + (l*DIM + d)*NK;
    const float* pdv = ud + (l*DIM + d)*(NK-1);
    const float* pl  = ul + (l*DIM + d)*NK;

    // widths softmax (serial-order rounding preserved)
    float ev[NK];
    float mw = pw[0];
    for (int j = 1; j < NK; ++j) mw = fmaxf(mw, pw[j]);
    float sw = 0.f;
    for (int j = 0; j < NK; ++j) { ev[j] = expf(pw[j] - mw); sw += ev[j]; }
    float invw = 1.f / sw;
    float cwe = 0.f, cwi = 0.f;
    for (int j = 0; j <= k; ++j) {
      float vj = 1e-3f + (1.f - 1e-3f * (float)NK) * (ev[j] * invw);
      cwe = cwi; cwi += vj;
    }
    float kwL = (k == 0) ? -3.f : 6.f * cwe - 3.f;
    float kwR = (k == 7) ?  3.f : 6.f * cwi - 3.f;
    float wwk = kwR - kwL;

    // heights softmax
    float mh = ph[0];
    for (int j = 1; j < NK; ++j) mh = fmaxf(mh, ph[j]);
    float sh = 0.f;
    for (int j = 0; j < NK; ++j) { ev[j] = expf(ph[j] - mh); sh += ev[j]; }
    float invh = 1.f / sh;
    float che = 0.f, chi = 0.f;
    for (int j = 0; j <= k; ++j) {
      float vj = 1e-3f + (1.f - 1e-3f * (float)NK) * (ev[j] * invh);
      che = chi; chi += vj;
    }
    float khL = (k == 0) ? -3.f : 6.f * che - 3.f;
    float khR = (k == 7) ?  3.f : 6.f * chi - 3.f;
    float hhk = khR - khL;

    // derivatives at both ends of bin k; lambda
    float dvk, dvk1;
    if (k == 0) dvk = 1.f;
    else { float u = pdv[k-1]; dvk  = 1e-3f + (fmaxf(u,0.f) + log1pf(expf(-fabsf(u)))); }
    if (k == 7) dvk1 = 1.f;
    else { float u = pdv[k];   dvk1 = 1e-3f + (fmaxf(u,0.f) + log1pf(expf(-fabsf(u)))); }
    float sg = 1.f / (1.f + expf(-pl[k]));
    float lmk = 0.95f * sg + 0.025f;

    float delta = hhk / wwk;
    float wbf = sqrtf(dvk / dvk1);
    float wcf = (lmk*dvk + (1.f-lmk)*wbf*dvk1) / delta;
    float yaf = khL, ybf = hhk + khL;
    float ycf = ((1.f-lmk)*yaf + lmk*wbf*ybf) / ((1.f-lmk) + lmk*wbf);

    if (k == 0) {
      Lb[l][0] = -3.0; Lb[l][16] = 3.0;
      Ly[l][0] = -3.0; Ly[l][16] = 3.0;
    }
    if (k) Lb[l][2*k] = (double)(kwL + 1.0e-6f);   // bin boundary (fp32 +EPS)
    Lb[l][2*k+1] = (double)kwL + (double)lmk*(double)wwk;  // theta==lambda
    Ly[l][2*k]   = (double)yaf;
    Ly[l][2*k+1] = (double)ycf;

    double icw = (double)kwL, iw = (double)wwk, il = (double)lmk;
    double wb = wbf, wc = wcf, ya = yaf, yb = ybf, yc = ycf;
    double n0 = ya*il, n1 = wc*yc - ya, d0 = il, d1 = wc - 1.0;
    double A = n1, Bv = n0*iw - n1*icw, C = d1, Dv = d0*iw - d1*icw;
    LM[l][2*k][0]=A; LM[l][2*k][1]=Bv; LM[l][2*k][2]=C; LM[l][2*k][3]=Dv;
    Ld[l][2*k] = log2(A*Dv - Bv*C);
    n0 = wc*yc - il*wb*yb; n1 = wb*yb - wc*yc; d0 = wc - il*wb; d1 = wb - wc;
    A = n1; Bv = n0*iw - n1*icw; C = d1; Dv = d0*iw - d1*icw;
    LM[l][2*k+1][0]=A; LM[l][2*k+1][1]=Bv; LM[l][2*k+1][2]=C; LM[l][2*k+1][3]=Dv;
    Ld[l][2*k+1] = log2(A*Dv - Bv*C);
  }
  __syncthreads();

  if (t < 60) {
    int lp  = t / 15;
    int mth = t % 15 + 1;
    double x = Lb[lp][mth];
    for (int q = lp - 1; q >= 0; --q) {
      int j = 0;
      for (int k = 1; k <= 15; ++k) j += (x >= Ly[q][k]) ? 1 : 0;
      const double* M = LM[q][j];
      x = (M[3]*x - M[1]) / (M[0] - M[2]*x);  // Mobius inverse
    }
    sx[t] = x;
  }
  __syncthreads();
  if (t < 60) {
    double x = sx[t];
    int r = 0;
    for (int s2 = 0; s2 < 60; ++s2) {
      double o = sx[s2];
      r += (o < x || (o == x && s2 < t)) ? 1 : 0;
    }
    Fb[r+1] = x;
  }
  if (t == 0)  Fb[0] = -3.0;
  if (t >= 60) Fb[t+1] = 3.0;   // Fb[61..64] geometry pads
  __syncthreads();

  // boundary slot table B[j]: B[0]=-3, B[1..60]=interior, B[61]=3, pads inf
  {
    int j = t;
    float bf;
    if (j == 0)       bf = -3.0f;
    else if (j <= 60) bf = (float)Fb[j];
    else if (j == 61) bf = 3.0f;
    else              bf = 1e30f;         // pads: never counted
    int cw = j >> 3, r8 = j & 7;
    if (r8 < 4) F[OFF_KN0 + (cw*DIM + d)*4 + r8]     = bf;
    else        F[OFF_KN1 + (cw*DIM + d)*4 + (r8-4)] = bf;
    if (j >= 8 && (j & 7) == 0 && j <= 56) F[OFF_CRS + (j/8 - 1)*DIM + d] = bf;
  }

  // coeff row t: rows 0, 62, 63 identity; rows 1..61 = interior piece t-1
  {
    float4 c4;
    if (t == 0 || t >= 62) {
      c4.x = 1.f; c4.y = 0.f; c4.z = 0.f; c4.w = 1.f;
    } else {
      int q = t - 1;
      double bl = Fb[q], br = Fb[q+1];
      float xmf = (float)(0.5*(bl+br));
      xmf = fminf(fmaxf(xmf, -3.f), 3.f);
      double y = (double)xmf;
      double A=1.0, Bv=0.0, C=0.0, Dv=1.0, ld2 = 0.0;
      for (int qq = 0; qq < NLAY; ++qq) {
        int j = 0;
        for (int k = 1; k <= 15; ++k) j += (y >= Lb[qq][k]) ? 1 : 0;
        const double* M = LM[qq][j];
        ld2 += Ld[qq][j];
        double A2 = M[0]*A + M[1]*C, B2 = M[0]*Bv + M[1]*Dv;
        double C2 = M[2]*A + M[3]*C, D2 = M[2]*Bv + M[3]*Dv;
        y = (M[0]*y + M[1]) / (M[2]*y + M[3]);
        A=A2; Bv=B2; C=C2; Dv=D2;
      }
      double sinv = exp2(-0.5 * ld2);              // det -> 1
      c4.x = (float)(A*sinv);  c4.y = (float)(Bv*sinv);
      c4.z = (float)(C*sinv);  c4.w = (float)(Dv*sinv);
    }
    *(float4*)(F + OFF_CF0 + (size_t)(t*DIM + d)*4) = c4;
  }
}

template <int CTRL>
__device__ __forceinline__ float dpp_add(float x) {
  // bound_ctrl=true: invalid source lanes read 0 -> folds to one v_add_f32_dpp
  int yi = __builtin_amdgcn_update_dpp(0, __float_as_int(x), CTRL, 0xF, 0xF, true);
  return x + __int_as_float(yi);
}
// wave64 sum -> lane 63 (rocPRIM gfx9 sequence)
__device__ __forceinline__ float wave_sum63(float x) {
  x = dpp_add<0x111>(x);  // row_shr:1
  x = dpp_add<0x112>(x);  // row_shr:2
  x = dpp_add<0x114>(x);  // row_shr:4
  x = dpp_add<0x118>(x);  // row_shr:8
  x = dpp_add<0x142>(x);  // row_bcast:15
  x = dpp_add<0x143>(x);  // row_bcast:31
  return x;
}

// linear counts on RAW x (ILP-friendly)
#define COARSE(xx) ((xx>=k1)+(xx>=k2)+(xx>=k3)+(xx>=k4)+(xx>=k5)+(xx>=k6)+(xx>=k7))
#define FINEI(xx, cc, f0, f1)                                                 \
  ((int)((xx) >= -3.f) + ((cc)<<3)                                            \
   + (int)((xx)>=f0.y)+(int)((xx)>=f0.z)+(int)((xx)>=f0.w)+(int)((xx)>=f1.x)  \
   + (int)((xx)>=f1.y)+(int)((xx)>=f1.z)+(int)((xx)>=f1.w))

// Main: lane = dim; wave owns 32 rows as 8 units of 4 rows, 2-slot pipeline:
//   R1: coarse(unit k+1)x4 + issue 8 fine-knot reads + X prefetch(unit k+2)
//   R2: math(unit k)x4 with coeffs read LAST STEP; float4 log-det store
//   R3: fine-count(unit k+1)x4 + issue 4 coeff reads
// 3 groups x 2 STEPs (+1 STEP +epilogue), group-local pointers (offsets
// <= 3840B fold into instructions).
__global__ __launch_bounds__(1024, 4) void nf_main(const float* __restrict__ X,
                                                   const float* __restrict__ F,
                                                   float* __restrict__ OUT,
                                                   float* __restrict__ LDo) {
  __shared__ float smem[20480];   // [0,4096): knots  [4096,20480): 64 coeff rows
  int t = threadIdx.x;
  {
    float4* dst = (float4*)smem;
    const float4* kt = (const float4*)(F + OFF_KN0);
    dst[t] = kt[t];
    const float4* ct = (const float4*)(F + OFF_CF0);
#pragma unroll
    for (int i = 0; i < 4; ++i) dst[1024 + t + i*1024] = ct[t + i*1024];
  }
  int d = t & 63;
  float k1 = F[OFF_CRS + 0*DIM + d];
  float k2 = F[OFF_CRS + 1*DIM + d];
  float k3 = F[OFF_CRS + 2*DIM + d];
  float k4 = F[OFF_CRS + 3*DIM + d];
  float k5 = F[OFF_CRS + 4*DIM + d];
  float k6 = F[OFF_CRS + 5*DIM + d];
  float k7 = F[OFF_CRS + 6*DIM + d];
  __syncthreads();
  const float4* skv = (const float4*)smem;

  int gw = blockIdx.x * 16 + (t >> 6);          // 0..8191; wave owns 32 rows
  const float* Xp = X   + (size_t)gw*32*DIM + d;
  float*       Op = OUT + (size_t)gw*32*DIM + d;
  float*       Lp = LDo + (size_t)gw*32;

  // ---- prologue: full search of unit 0; load x of unit 1 ----
  float xA0 = Xp[0],   xA1 = Xp[64],  xA2 = Xp[128], xA3 = Xp[192];
  float xB0 = Xp[256], xB1 = Xp[320], xB2 = Xp[384], xB3 = Xp[448];
  float4 cfA0, cfA1, cfA2, cfA3;
  {
    int c0 = COARSE(xA0), c1 = COARSE(xA1), c2 = COARSE(xA2), c3 = COARSE(xA3);
    float4 f00 = skv[(c0<<6)+d], f01 = skv[512+(c0<<6)+d];
    float4 f10 = skv[(c1<<6)+d], f11 = skv[512+(c1<<6)+d];
    float4 f20 = skv[(c2<<6)+d], f21 = skv[512+(c2<<6)+d];
    float4 f30 = skv[(c3<<6)+d], f31 = skv[512+(c3<<6)+d];
    int p0 = FINEI(xA0, c0, f00, f01);
    int p1 = FINEI(xA1, c1, f10, f11);
    int p2 = FINEI(xA2, c2, f20, f21);
    int p3 = FINEI(xA3, c3, f30, f31);
    cfA0 = skv[1024+(p0<<6)+d];
    cfA1 = skv[1024+(p1<<6)+d];
    cfA2 = skv[1024+(p2<<6)+d];
    cfA3 = skv[1024+(p3<<6)+d];
  }

  // STEP(u = unit-in-group 0/1, lo = prefetch unit rel to group base)
#define STEP(u, lo)                                                            \
  {                                                                            \
    /* R1: coarse(next unit) x4, issue 8 fine-knot reads; prefetch x */        \
    int cB0 = COARSE(xB0), cB1 = COARSE(xB1);                                  \
    int cB2 = COARSE(xB2), cB3 = COARSE(xB3);                                  \
    float4 f00 = skv[(cB0<<6)+d], f01 = skv[512+(cB0<<6)+d];                   \
    float4 f10 = skv[(cB1<<6)+d], f11 = skv[512+(cB1<<6)+d];                   \
    float4 f20 = skv[(cB2<<6)+d], f21 = skv[512+(cB2<<6)+d];                   \
    float4 f30 = skv[(cB3<<6)+d], f31 = skv[512+(cB3<<6)+d];                   \
    float xF0 = Xp[(lo)*256],       xF1 = Xp[(lo)*256 + 64];                   \
    float xF2 = Xp[(lo)*256 + 128], xF3 = Xp[(lo)*256 + 192];                  \
    __builtin_amdgcn_sched_barrier(0);                                         \
    /* R2: math(current unit) x4 using cfA (read LAST STEP) */                 \
    float num0 = fmaf(cfA0.x, xA0, cfA0.y);                                    \
    float den0 = fmaf(cfA0.z, xA0, cfA0.w);                                    \
    float o0 = __fdividef(num0, den0);                                         \
    float l0 = __log2f(fabsf(den0));                                           \
    float num1 = fmaf(cfA1.x, xA1, cfA1.y);                                    \
    float den1 = fmaf(cfA1.z, xA1, cfA1.w);                                    \
    float o1 = __fdividef(num1, den1);                                         \
    float l1 = __log2f(fabsf(den1));                                           \
    float num2 = fmaf(cfA2.x, xA2, cfA2.y);                                    \
    float den2 = fmaf(cfA2.z, xA2, cfA2.w);                                    \
    float o2 = __fdividef(num2, den2);                                         \
    float l2 = __log2f(fabsf(den2));                                           \
    float num3 = fmaf(cfA3.x, xA3, cfA3.y);                                    \
    float den3 = fmaf(cfA3.z, xA3, cfA3.w);                                    \
    float o3 = __fdividef(num3, den3);                                         \
    float l3 = __log2f(fabsf(den3));                                           \
    Op[(u)*256]       = o0;                                                    \
    Op[(u)*256 + 64]  = o1;                                                    \
    Op[(u)*256 + 128] = o2;                                                    \
    Op[(u)*256 + 192] = o3;                                                    \
    float s0 = wave_sum63(l0);                                                 \
    float s1 = wave_sum63(l1);                                                 \
    float s2 = wave_sum63(l2);                                                 \
    float s3 = wave_sum63(l3);                                                 \
    if (d == 63) {                                                             \
      float4 v;                                                                \
      v.x = s0 * -1.3862943611198906f;                                         \
      v.y = s1 * -1.3862943611198906f;                                         \
      v.z = s2 * -1.3862943611198906f;                                         \
      v.w = s3 * -1.3862943611198906f;                                         \
      *(float4*)(Lp + 4*(u)) = v;                                              \
    }                                                                          \
    __builtin_amdgcn_sched_barrier(0);                                         \
    /* R3: fine-count(next unit) x4 + issue 4 coeff reads */                   \
    int p0 = FINEI(xB0, cB0, f00, f01);                                        \
    int p1 = FINEI(xB1, cB1, f10, f11);                                        \
    int p2 = FINEI(xB2, cB2, f20, f21);                                        \
    int p3 = FINEI(xB3, cB3, f30, f31);                                        \
    cfA0 = skv[1024+(p0<<6)+d];                                                \
    cfA1 = skv[1024+(p1<<6)+d];                                                \
    cfA2 = skv[1024+(p2<<6)+d];                                                \
    cfA3 = skv[1024+(p3<<6)+d];                                                \
    xA0 = xB0; xA1 = xB1; xA2 = xB2; xA3 = xB3;                                \
    xB0 = xF0; xB1 = xF1; xB2 = xF2; xB3 = xF3;                                \
  }

  for (int g = 0; g < 3; ++g) {
    STEP(0, 2)
    STEP(1, 3)
    Xp += 512; Op += 512; Lp += 8;
  }
  STEP(0, 1)          // unit 6: prefetch clamps to unit 7 (redundant reload)
  // ---- epilogue: math(unit 7) at rel offset 256 ----
  {
    float num0 = fmaf(cfA0.x, xA0, cfA0.y);
    float den0 = fmaf(cfA0.z, xA0, cfA0.w);
    float o0 = __fdividef(num0, den0);
    float l0 = __log2f(fabsf(den0));
    float num1 = fmaf(cfA1.x, xA1, cfA1.y);
    float den1 = fmaf(cfA1.z, xA1, cfA1.w);
    float o1 = __fdividef(num1, den1);
    float l1 = __log2f(fabsf(den1));
    float num2 = fmaf(cfA2.x, xA2, cfA2.y);
    float den2 = fmaf(cfA2.z, xA2, cfA2.w);
    float o2 = __fdividef(num2, den2);
    float l2 = __log2f(fabsf(den2));
    float num3 = fmaf(cfA3.x, xA3, cfA3.y);
    float den3 = fmaf(cfA3.z, xA3, cfA3.w);
    float o3 = __fdividef(num3, den3);
    float l3 = __log2f(fabsf(den3));
    Op[256] = o0; Op[320] = o1; Op[384] = o2; Op[448] = o3;
    float s0 = wave_sum63(l0);
    float s1 = wave_sum63(l1);
    float s2 = wave_sum63(l2);
    float s3 = wave_sum63(l3);
    if (d == 63) {
      float4 v;
      v.x = s0 * -1.3862943611198906f;
      v.y = s1 * -1.3862943611198906f;
      v.z = s2 * -1.3862943611198906f;
      v.w = s3 * -1.3862943611198906f;
      *(float4*)(Lp + 4) = v;
    }
  }
#undef STEP
}

extern "C" void kernel_launch(void* const* d_in, const int* in_sizes, int n_in,
                              void* d_out, int out_size, void* d_ws, size_t ws_size,
                              hipStream_t stream) {
  const float* x  = (const float*)d_in[0];
  const float* uw = (const float*)d_in[1];
  const float* uh = (const float*)d_in[2];
  const float* ud = (const float*)d_in[3];
  const float* ul = (const float*)d_in[4];
  float* out = (float*)d_out;
  float* F = (float*)d_ws;
  nf_pre<<<DIM, 64, 0, stream>>>(uw, uh, ud, ul, F);
  nf_main<<<512, 1024, 0, stream>>>(x, F, out, out + (size_t)BATCH*DIM);
}

// Round 17
// 42.775 us; speedup vs baseline: 1.1564x; 1.1564x over previous
//
#include <hip/hip_runtime.h>

// NormalizingFlow: 4 layers of monotonic linear-rational splines (pyro-style),
// B=262144 rows, D=64 dims, K=8 bins.
//
// Composed 4-layer chain per dim = piecewise-Mobius: 61 interior pieces +
// identity pieces (x<-3 row 0, x>=3 rows 62/63), det-normalized (det=1)
// ABSOLUTE fp32 coeffs, 64-row table. Main kernel (lane = dim, natural
// columns, conflict-free): linear counts on RAW x —
//   row = (x>=-3) + sum(x>=B[8m], m=1..7) + sum(x>=B[8c+1..8c+7])
// (B[61]=3.0) + one b128 coeff gather + Mobius; lad = -2 ln|den|; DPP reduce.
// No clamp / no outside-select. 2-slot pipeline + sched_barrier(0);
// 3 groups x 5 units, group-local pointers (folded offsets).
// Best-measured configuration (R15: 42.74us total, main ~36us).

#define BATCH 262144
#define DIM   64
#define NLAY  4
#define NK    8

// float offsets in d_ws (units: floats from base)
#define OFF_KN0 0       // [8][64][4] boundary slots B[8c+0..3]
#define OFF_KN1 2048    // [8][64][4] boundary slots B[8c+4..7]
#define OFF_CRS 4096    // [7][64] coarse knots B[8],B[16],...,B[56]
#define OFF_CF0 4544    // [64][64][4] piece coeffs (A,B,C,D); rows 0,62,63 id

// Fused precompute: one block per dim d (64 blocks x 64 threads).
// Phase 1 parallelized over 32 threads: t = l*8 + k (layer l, bin k).
__global__ void nf_pre(const float* __restrict__ uw, const float* __restrict__ uh,
                       const float* __restrict__ ud, const float* __restrict__ ul,
                       float* __restrict__ F) {
  __shared__ double Lb[NLAY][17], Ly[NLAY][17], LM[NLAY][16][4], Ld[NLAY][16];
  __shared__ double sx[64], Fb[65];
  int d = blockIdx.x;
  int t = threadIdx.x;

  if (t < 32) {
    int l = t >> 3, k = t & 7;
    const float* pw  = uw + (l*DIM + d)*NK;
    const float* ph  = uh + (l*DIM + d)*NK;
    const float* pdv = ud + (l*DIM + d)*(NK-1);
    const float* pl  = ul + (l*DIM + d)*NK;

    // widths softmax (serial-order rounding preserved)
    float ev[NK];
    float mw = pw[0];
    for (int j = 1; j < NK; ++j) mw = fmaxf(mw, pw[j]);
    float sw = 0.f;
    for (int j = 0; j < NK; ++j) { ev[j] = expf(pw[j] - mw); sw += ev[j]; }
    float invw = 1.f / sw;
    float cwe = 0.f, cwi = 0.f;
    for (int j = 0; j <= k; ++j) {
      float vj = 1e-3f + (1.f - 1e-3f * (float)NK) * (ev[j] * invw);
      cwe = cwi; cwi += vj;
    }
    float kwL = (k == 0) ? -3.f : 6.f * cwe - 3.f;
    float kwR = (k == 7) ?  3.f : 6.f * cwi - 3.f;
    float wwk = kwR - kwL;

    // heights softmax
    float mh = ph[0];
    for (int j = 1; j < NK; ++j) mh = fmaxf(mh, ph[j]);
    float sh = 0.f;
    for (int j = 0; j < NK; ++j) { ev[j] = expf(ph[j] - mh); sh += ev[j]; }
    float invh = 1.f / sh;
    float che = 0.f, chi = 0.f;
    for (int j = 0; j <= k; ++j) {
      float vj = 1e-3f + (1.f - 1e-3f * (float)NK) * (ev[j] * invh);
      che = chi; chi += vj;
    }
    float khL = (k == 0) ? -3.f : 6.f * che - 3.f;
    float khR = (k == 7) ?  3.f : 6.f * chi - 3.f;
    float hhk = khR - khL;

    // derivatives at both ends of bin k; lambda
    float dvk, dvk1;
    if (k == 0) dvk = 1.f;
    else { float u = pdv[k-1]; dvk  = 1e-3f + (fmaxf(u,0.f) + log1pf(expf(-fabsf(u)))); }
    if (k == 7) dvk1 = 1.f;
    else { float u = pdv[k];   dvk1 = 1e-3f + (fmaxf(u,0.f) + log1pf(expf(-fabsf(u)))); }
    float sg = 1.f / (1.f + expf(-pl[k]));
    float lmk = 0.95f * sg + 0.025f;

    float delta = hhk / wwk;
    float wbf = sqrtf(dvk / dvk1);
    float wcf = (lmk*dvk + (1.f-lmk)*wbf*dvk1) / delta;
    float yaf = khL, ybf = hhk + khL;
    float ycf = ((1.f-lmk)*yaf + lmk*wbf*ybf) / ((1.f-lmk) + lmk*wbf);

    if (k == 0) {
      Lb[l][0] = -3.0; Lb[l][16] = 3.0;
      Ly[l][0] = -3.0; Ly[l][16] = 3.0;
    }
    if (k) Lb[l][2*k] = (double)(kwL + 1.0e-6f);   // bin boundary (fp32 +EPS)
    Lb[l][2*k+1] = (double)kwL + (double)lmk*(double)wwk;  // theta==lambda
    Ly[l][2*k]   = (double)yaf;
    Ly[l][2*k+1] = (double)ycf;

    double icw = (double)kwL, iw = (double)wwk, il = (double)lmk;
    double wb = wbf, wc = wcf, ya = yaf, yb = ybf, yc = ycf;
    double n0 = ya*il, n1 = wc*yc - ya, d0 = il, d1 = wc - 1.0;
    double A = n1, Bv = n0*iw - n1*icw, C = d1, Dv = d0*iw - d1*icw;
    LM[l][2*k][0]=A; LM[l][2*k][1]=Bv; LM[l][2*k][2]=C; LM[l][2*k][3]=Dv;
    Ld[l][2*k] = log2(A*Dv - Bv*C);
    n0 = wc*yc - il*wb*yb; n1 = wb*yb - wc*yc; d0 = wc - il*wb; d1 = wb - wc;
    A = n1; Bv = n0*iw - n1*icw; C = d1; Dv = d0*iw - d1*icw;
    LM[l][2*k+1][0]=A; LM[l][2*k+1][1]=Bv; LM[l][2*k+1][2]=C; LM[l][2*k+1][3]=Dv;
    Ld[l][2*k+1] = log2(A*Dv - Bv*C);
  }
  __syncthreads();

  if (t < 60) {
    int lp  = t / 15;
    int mth = t % 15 + 1;
    double x = Lb[lp][mth];
    for (int q = lp - 1; q >= 0; --q) {
      int j = 0;
      for (int k = 1; k <= 15; ++k) j += (x >= Ly[q][k]) ? 1 : 0;
      const double* M = LM[q][j];
      x = (M[3]*x - M[1]) / (M[0] - M[2]*x);  // Mobius inverse
    }
    sx[t] = x;
  }
  __syncthreads();
  if (t < 60) {
    double x = sx[t];
    int r = 0;
    for (int s2 = 0; s2 < 60; ++s2) {
      double o = sx[s2];
      r += (o < x || (o == x && s2 < t)) ? 1 : 0;
    }
    Fb[r+1] = x;
  }
  if (t == 0)  Fb[0] = -3.0;
  if (t >= 60) Fb[t+1] = 3.0;   // Fb[61..64] geometry pads
  __syncthreads();

  // boundary slot table B[j]: B[0]=-3, B[1..60]=interior, B[61]=3, pads inf
  {
    int j = t;
    float bf;
    if (j == 0)       bf = -3.0f;
    else if (j <= 60) bf = (float)Fb[j];
    else if (j == 61) bf = 3.0f;
    else              bf = 1e30f;         // pads: never counted
    int cw = j >> 3, r8 = j & 7;
    if (r8 < 4) F[OFF_KN0 + (cw*DIM + d)*4 + r8]     = bf;
    else        F[OFF_KN1 + (cw*DIM + d)*4 + (r8-4)] = bf;
    if (j >= 8 && (j & 7) == 0 && j <= 56) F[OFF_CRS + (j/8 - 1)*DIM + d] = bf;
  }

  // coeff row t: rows 0, 62, 63 identity; rows 1..61 = interior piece t-1
  {
    float4 c4;
    if (t == 0 || t >= 62) {
      c4.x = 1.f; c4.y = 0.f; c4.z = 0.f; c4.w = 1.f;
    } else {
      int q = t - 1;
      double bl = Fb[q], br = Fb[q+1];
      float xmf = (float)(0.5*(bl+br));
      xmf = fminf(fmaxf(xmf, -3.f), 3.f);
      double y = (double)xmf;
      double A=1.0, Bv=0.0, C=0.0, Dv=1.0, ld2 = 0.0;
      for (int qq = 0; qq < NLAY; ++qq) {
        int j = 0;
        for (int k = 1; k <= 15; ++k) j += (y >= Lb[qq][k]) ? 1 : 0;
        const double* M = LM[qq][j];
        ld2 += Ld[qq][j];
        double A2 = M[0]*A + M[1]*C, B2 = M[0]*Bv + M[1]*Dv;
        double C2 = M[2]*A + M[3]*C, D2 = M[2]*Bv + M[3]*Dv;
        y = (M[0]*y + M[1]) / (M[2]*y + M[3]);
        A=A2; Bv=B2; C=C2; Dv=D2;
      }
      double sinv = exp2(-0.5 * ld2);              // det -> 1
      c4.x = (float)(A*sinv);  c4.y = (float)(Bv*sinv);
      c4.z = (float)(C*sinv);  c4.w = (float)(Dv*sinv);
    }
    *(float4*)(F + OFF_CF0 + (size_t)(t*DIM + d)*4) = c4;
  }
}

template <int CTRL>
__device__ __forceinline__ float dpp_add(float x) {
  // bound_ctrl=true: invalid source lanes read 0 -> folds to one v_add_f32_dpp
  int yi = __builtin_amdgcn_update_dpp(0, __float_as_int(x), CTRL, 0xF, 0xF, true);
  return x + __int_as_float(yi);
}
// wave64 sum -> lane 63 (rocPRIM gfx9 sequence)
__device__ __forceinline__ float wave_sum63(float x) {
  x = dpp_add<0x111>(x);  // row_shr:1
  x = dpp_add<0x112>(x);  // row_shr:2
  x = dpp_add<0x114>(x);  // row_shr:4
  x = dpp_add<0x118>(x);  // row_shr:8
  x = dpp_add<0x142>(x);  // row_bcast:15
  x = dpp_add<0x143>(x);  // row_bcast:31
  return x;
}

// linear counts on RAW x (ILP-friendly form)
#define COARSE(xx) ((xx>=k1)+(xx>=k2)+(xx>=k3)+(xx>=k4)+(xx>=k5)+(xx>=k6)+(xx>=k7))
#define FINEI(xx, cc, f0, f1)                                                 \
  ((int)((xx) >= -3.f) + ((cc)<<3)                                            \
   + (int)((xx)>=f0.y)+(int)((xx)>=f0.z)+(int)((xx)>=f0.w)+(int)((xx)>=f1.x)  \
   + (int)((xx)>=f1.y)+(int)((xx)>=f1.z)+(int)((xx)>=f1.w))

// Main: lane = dim; wave owns 32 rows as 16 units of 2, software-pipelined:
//   R1: coarse(unit k+1) + issue fine-knot reads + X prefetch(unit k+2)
//   R2: math(unit k) with coeffs read LAST iteration (latency hidden)
//   R3: fine-count(unit k+1) + issue coeff reads
// 3 groups x (unroll 5) with group-local pointers: all global offsets <= 2304B
// fold into the load/store instructions.
__global__ __launch_bounds__(1024, 4) void nf_main(const float* __restrict__ X,
                                                   const float* __restrict__ F,
                                                   float* __restrict__ OUT,
                                                   float* __restrict__ LDo) {
  __shared__ float smem[20480];   // [0,4096): knots  [4096,20480): 64 coeff rows
  int t = threadIdx.x;
  {
    float4* dst = (float4*)smem;
    const float4* kt = (const float4*)(F + OFF_KN0);
    dst[t] = kt[t];
    const float4* ct = (const float4*)(F + OFF_CF0);
#pragma unroll
    for (int i = 0; i < 4; ++i) dst[1024 + t + i*1024] = ct[t + i*1024];
  }
  int d = t & 63;
  float k1 = F[OFF_CRS + 0*DIM + d];
  float k2 = F[OFF_CRS + 1*DIM + d];
  float k3 = F[OFF_CRS + 2*DIM + d];
  float k4 = F[OFF_CRS + 3*DIM + d];
  float k5 = F[OFF_CRS + 4*DIM + d];
  float k6 = F[OFF_CRS + 5*DIM + d];
  float k7 = F[OFF_CRS + 6*DIM + d];
  __syncthreads();
  const float4* skv = (const float4*)smem;

  int gw = blockIdx.x * 16 + (t >> 6);          // 0..8191; wave owns 32 rows
  const float* Xp = X   + (size_t)gw*32*DIM + d;
  float*       Op = OUT + (size_t)gw*32*DIM + d;
  float*       Lp = LDo + (size_t)gw*32;

  // ---- prologue: full search of unit 0; load x of unit 1 ----
  float xA0 = Xp[0], xA1 = Xp[64];
  float xB0 = Xp[128], xB1 = Xp[192];
  float4 cfA0, cfA1;
  {
    int c0 = COARSE(xA0), c1 = COARSE(xA1);
    float4 f00 = skv[(c0<<6)+d], f01 = skv[512+(c0<<6)+d];
    float4 f10 = skv[(c1<<6)+d], f11 = skv[512+(c1<<6)+d];
    int p0 = FINEI(xA0, c0, f00, f01);
    int p1 = FINEI(xA1, c1, f10, f11);
    cfA0 = skv[1024+(p0<<6)+d];
    cfA1 = skv[1024+(p1<<6)+d];
  }

  for (int g = 0; g < 3; ++g) {
#pragma unroll
    for (int u = 0; u < 5; ++u) {
      // ---- R1: coarse(next unit), issue fine reads; prefetch x(unit+2) ----
      int cB0 = COARSE(xB0), cB1 = COARSE(xB1);
      float4 f00 = skv[(cB0<<6)+d], f01 = skv[512+(cB0<<6)+d];
      float4 f10 = skv[(cB1<<6)+d], f11 = skv[512+(cB1<<6)+d];
      int lo = (u == 4) ? ((g == 2) ? 5 : 6) : (u + 2);   // group-local prefetch
      float xF0 = Xp[lo*128], xF1 = Xp[lo*128 + 64];
      __builtin_amdgcn_sched_barrier(0);
      // ---- R2: math(unit g*5+u) using cfA (read last iteration) ----
      float num0 = fmaf(cfA0.x, xA0, cfA0.y);
      float den0 = fmaf(cfA0.z, xA0, cfA0.w);
      float o0 = __fdividef(num0, den0);
      float l0 = __log2f(fabsf(den0));
      float num1 = fmaf(cfA1.x, xA1, cfA1.y);
      float den1 = fmaf(cfA1.z, xA1, cfA1.w);
      float o1 = __fdividef(num1, den1);
      float l1 = __log2f(fabsf(den1));
      Op[u*128] = o0; Op[u*128 + 64] = o1;
      float s0 = wave_sum63(l0);
      float s1 = wave_sum63(l1);
      if (d == 63) {
        float2 v;
        v.x = s0 * -1.3862943611198906f;   // -2*ln2 folded once per row
        v.y = s1 * -1.3862943611198906f;
        *(float2*)(Lp + 2*u) = v;
      }
      __builtin_amdgcn_sched_barrier(0);
      // ---- R3: fine-count(next unit) + issue coeff reads ----
      int p0 = FINEI(xB0, cB0, f00, f01);
      int p1 = FINEI(xB1, cB1, f10, f11);
      cfA0 = skv[1024+(p0<<6)+d];
      cfA1 = skv[1024+(p1<<6)+d];
      xA0 = xB0; xA1 = xB1;
      xB0 = xF0; xB1 = xF1;
    }
    Xp += 640; Op += 640; Lp += 10;
  }
  // ---- epilogue: math(unit 15); Op/Lp now point at its slots ----
  {
    float num0 = fmaf(cfA0.x, xA0, cfA0.y);
    float den0 = fmaf(cfA0.z, xA0, cfA0.w);
    float o0 = __fdividef(num0, den0);
    float l0 = __log2f(fabsf(den0));
    float num1 = fmaf(cfA1.x, xA1, cfA1.y);
    float den1 = fmaf(cfA1.z, xA1, cfA1.w);
    float o1 = __fdividef(num1, den1);
    float l1 = __log2f(fabsf(den1));
    Op[0] = o0; Op[64] = o1;
    float s0 = wave_sum63(l0);
    float s1 = wave_sum63(l1);
    if (d == 63) {
      float2 v;
      v.x = s0 * -1.3862943611198906f;
      v.y = s1 * -1.3862943611198906f;
      *(float2*)Lp = v;
    }
  }
}

extern "C" void kernel_launch(void* const* d_in, const int* in_sizes, int n_in,
                              void* d_out, int out_size, void* d_ws, size_t ws_size,
                              hipStream_t stream) {
  const float* x  = (const float*)d_in[0];
  const float* uw = (const float*)d_in[1];
  const float* uh = (const float*)d_in[2];
  const float* ud = (const float*)d_in[3];
  const float* ul = (const float*)d_in[4];
  float* out = (float*)d_out;
  float* F = (float*)d_ws;
  nf_pre<<<DIM, 64, 0, stream>>>(uw, uh, ud, ul, F);
  nf_main<<<512, 1024, 0, stream>>>(x, F, out, out + (size_t)BATCH*DIM);
}